// Round 11
// baseline (126.827 us; speedup 1.0000x reference)
//
#include <hip/hip_runtime.h>
#include <hip/hip_bf16.h>

#define DIM   1024
#define HEADS 16
#define B     2
#define N     2048
#define ROWS_PER_BLK 8   // fused outer: 8 output rows per block -> 8192 blocks

typedef float f32x4 __attribute__((ext_vector_type(4)));

__device__ __forceinline__ float logsig(float z) {
  return fminf(z, 0.0f) - log1pf(__expf(-fabsf(z)));
}

// ---------------------------------------------------------------------------
// Kernel 1: logits[b,h,n] = dot(x[b,n,:], W[h,:]) + bias[h]
// One block per (b,n). 256 threads = 4 waves; each wave computes 4 heads.
// ---------------------------------------------------------------------------
__global__ __launch_bounds__(256) void logits_kernel(
    const float* __restrict__ x, const float* __restrict__ W,
    const float* __restrict__ bias, float* __restrict__ logits) {
  const int bn   = blockIdx.x;
  const int tid  = threadIdx.x;
  const int wave = tid >> 6;
  const int lane = tid & 63;

  const f32x4* xrow = (const f32x4*)(x + (size_t)bn * DIM);
  f32x4 xv[4];
#pragma unroll
  for (int k = 0; k < 4; ++k) xv[k] = xrow[lane * 4 + k];

#pragma unroll
  for (int hh = 0; hh < 4; ++hh) {
    const int h = wave * 4 + hh;
    const f32x4* wrow = (const f32x4*)(W + (size_t)h * DIM);
    float s = 0.0f;
#pragma unroll
    for (int k = 0; k < 4; ++k) {
      f32x4 wv = wrow[lane * 4 + k];
      s += wv.x * xv[k].x + wv.y * xv[k].y + wv.z * xv[k].z + wv.w * xv[k].w;
    }
#pragma unroll
    for (int off = 32; off > 0; off >>= 1) s += __shfl_down(s, off, 64);
    if (lane == 0) {
      const int b = bn >> 11;
      const int n = bn & (N - 1);
      logits[((size_t)(b * HEADS + h)) * N + n] = s + bias[h];
    }
  }
}

// ---------------------------------------------------------------------------
// Kernel 2 (fused cumsum + outer): each block recomputes its bh's fg row into
// LDS, then writes 8 output rows with the r4 store pattern (all 4 waves
// jointly write one 8 KB row, rows consecutive). 8192 blocks, 1/4 co-resident
// -> block start/finish staggered so prologues overlap other blocks' stores.
// ---------------------------------------------------------------------------
__global__ __launch_bounds__(256) void fused_outer_kernel(
    const float* __restrict__ logits, float* __restrict__ out) {
  const int blk  = blockIdx.x;        // 0..8191
  const int bh   = blk >> 8;          // 256 blocks per bh
  const int i0   = (blk & 255) * ROWS_PER_BLK;
  const int tid  = threadIdx.x;
  const int lane = tid & 63;
  const int wave = tid >> 6;

  __shared__ float fgrow[N];          // 8 KB: the cumsum row for this bh
  __shared__ float wtot[4];

  // ---- prologue: fg row = cumsum(logsig(logits[bh,:])) (identical math)
  {
    const float* lp = logits + (size_t)bh * N;
    f32x4 a = ((const f32x4*)lp)[tid * 2];
    f32x4 c = ((const f32x4*)lp)[tid * 2 + 1];
    float v[8] = {a.x, a.y, a.z, a.w, c.x, c.y, c.z, c.w};

    float run = 0.0f;
#pragma unroll
    for (int i = 0; i < 8; ++i) { v[i] = logsig(v[i]); run += v[i]; v[i] = run; }
    const float total = run;

    float sc = total;
#pragma unroll
    for (int off = 1; off < 64; off <<= 1) {
      float t = __shfl_up(sc, off, 64);
      if (lane >= off) sc += t;
    }
    if (lane == 63) wtot[wave] = sc;
    __syncthreads();
    float wofs = 0.0f;
    for (int w = 0; w < wave; ++w) wofs += wtot[w];

    const float base = wofs + sc - total;   // exclusive prefix for this thread
    f32x4 o0 = {base + v[0], base + v[1], base + v[2], base + v[3]};
    f32x4 o1 = {base + v[4], base + v[5], base + v[6], base + v[7]};
    ((f32x4*)fgrow)[tid * 2]     = o0;
    ((f32x4*)fgrow)[tid * 2 + 1] = o1;
  }
  __syncthreads();

  // ---- epilogue: 8 rows, r4 store pattern (block writes each row jointly)
  const f32x4 v0 = ((const f32x4*)fgrow)[tid];
  const f32x4 v1 = ((const f32x4*)fgrow)[tid + 256];

  f32x4* orow = (f32x4*)(out + ((size_t)(bh * N + i0)) * N);
#pragma unroll
  for (int r = 0; r < ROWS_PER_BLK; ++r) {
    const float f = fgrow[i0 + r];    // LDS broadcast
    f32x4 r0 = {f - v0.x, f - v0.y, f - v0.z, f - v0.w};
    f32x4 r1 = {f - v1.x, f - v1.y, f - v1.z, f - v1.w};
    orow[tid]       = r0;
    orow[tid + 256] = r1;
    orow += N / 4;                    // next consecutive row
  }
}

extern "C" void kernel_launch(void* const* d_in, const int* in_sizes, int n_in,
                              void* d_out, int out_size, void* d_ws, size_t ws_size,
                              hipStream_t stream) {
  const float* x    = (const float*)d_in[0];   // [B, N, DIM]
  const float* W    = (const float*)d_in[1];   // [HEADS, DIM]
  const float* bias = (const float*)d_in[2];   // [HEADS]
  float* out = (float*)d_out;                  // [B, HEADS, N, N]

  float* logits = (float*)d_ws;                // 256 KB scratch

  logits_kernel<<<B * N, 256, 0, stream>>>(x, W, bias, logits);
  fused_outer_kernel<<<B * HEADS * (N / ROWS_PER_BLK), 256, 0, stream>>>(logits, out);
}